// Round 8
// baseline (433.981 us; speedup 1.0000x reference)
//
#include <hip/hip_runtime.h>
#include <hip/hip_bf16.h>
#include <cstdint>

// Problem constants
#define Bb 4
#define Ss 4096
#define Dd 1024
#define Hh 8
#define DI 2048
#define HD 256
#define XZN 4096      // 2*DI
#define Mtot 16384    // B*S
#define NCH 128       // scan chunks
#define CHUNK 32      // S / NCH

typedef __bf16 bf16_t;
typedef __bf16 bf16x8 __attribute__((ext_vector_type(8)));
typedef __bf16 bf16x4 __attribute__((ext_vector_type(4)));
typedef float f32x4 __attribute__((ext_vector_type(4)));

__device__ __forceinline__ float sigmoidf_(float x) { return 1.f / (1.f + __expf(-x)); }

// async 16B/lane global->LDS. LDS dest is wave-uniform base + lane*16.
__device__ __forceinline__ void async_ld16(void* lds, const void* g) {
  __builtin_amdgcn_global_load_lds(
      (const __attribute__((address_space(1))) void*)(uintptr_t)g,
      (__attribute__((address_space(3))) void*)(uint32_t)(uintptr_t)lds,
      16, 0, 0);
}

// ---------------- fp32 -> bf16 cast (both weights, one launch) ----------------
__global__ __launch_bounds__(256) void cvt2_kernel(const float* __restrict__ a,
                                                   bf16_t* __restrict__ da,
                                                   const float* __restrict__ b,
                                                   bf16_t* __restrict__ db) {
  const int na = (2 * DI * Dd) / 4;   // 1M float4 units for in_proj_w
  int i = blockIdx.x * 256 + threadIdx.x;
  const float* s;
  bf16_t* o;
  if (i < na) { s = a; o = da + 4 * (size_t)i; }
  else        { i -= na; s = b; o = db + 4 * (size_t)i; }
  const float4 v = ((const float4*)s)[i];
  o[0] = (bf16_t)v.x; o[1] = (bf16_t)v.y; o[2] = (bf16_t)v.z; o[3] = (bf16_t)v.w;
}

// ---------------- LayerNorm -> bf16 ----------------
__global__ __launch_bounds__(256) void ln_kernel(const float* __restrict__ x,
                                                 const float* __restrict__ w,
                                                 const float* __restrict__ b,
                                                 bf16_t* __restrict__ xn) {
  __shared__ float red[8];
  const int row = blockIdx.x;
  const float4 v = ((const float4*)(x + (size_t)row * Dd))[threadIdx.x];
  float s  = v.x + v.y + v.z + v.w;
  float s2 = v.x * v.x + v.y * v.y + v.z * v.z + v.w * v.w;
  #pragma unroll
  for (int off = 32; off; off >>= 1) { s += __shfl_down(s, off); s2 += __shfl_down(s2, off); }
  const int wave = threadIdx.x >> 6, lane = threadIdx.x & 63;
  if (lane == 0) { red[wave * 2] = s; red[wave * 2 + 1] = s2; }
  __syncthreads();
  if (threadIdx.x == 0) {
    float S = 0.f, S2 = 0.f;
    for (int i = 0; i < 4; ++i) { S += red[i * 2]; S2 += red[i * 2 + 1]; }
    red[0] = S; red[1] = S2;
  }
  __syncthreads();
  const float mean = red[0] * (1.f / Dd);
  const float var  = red[1] * (1.f / Dd) - mean * mean;
  const float rstd = rsqrtf(var + 1e-5f);
  const float4 wv = ((const float4*)w)[threadIdx.x];
  const float4 bv = ((const float4*)b)[threadIdx.x];
  bf16_t* o = xn + (size_t)row * Dd + threadIdx.x * 4;
  o[0] = (bf16_t)((v.x - mean) * rstd * wv.x + bv.x);
  o[1] = (bf16_t)((v.y - mean) * rstd * wv.y + bv.y);
  o[2] = (bf16_t)((v.z - mean) * rstd * wv.z + bv.z);
  o[3] = (bf16_t)((v.w - mean) * rstd * wv.w + bv.w);
}

// ---------------- GEMM: C[M,N] = A[M,K] @ B[N,K]^T (both K-major bf16) ----------------
// Round-4 skeleton (best measured: GEMM1 135.9us, conflicts==0), templated on
// wave grid so GEMM2 can run 128x128 tiles at 2 blocks/CU (its 256-block 1/CU
// single-round config left prologue fill + epilogue burst fully exposed).
//   WM x WN waves, each wave MT x NTT 16x16 frags (wave out = MT*16 x NTT*16).
//   BM = WM*MT*16 == BN = WN*NTT*16. BK=64, 16x16x32 bf16 MFMA.
// LDS: 2 dbufs (tile parity) x (A | B), each matrix 2 K-half regions (ks0/ks1)
// of [BM rows][32 K] with 64B rows, XOR swizzle phys_chunk = logical^((row>>1)&3)
// (measured conflict-free). Staging: region = 2 async_ld16 calls (WAVES*16 rows
// each), pre-swizzled source column group (l&3)^((l>>3)&3).
// Ledger (8 loads/tile): tile-top vmcnt(4)+barrier retires A-ks0,B-ks0; stage
// next A-ks0/B-ks0 during ks0 phases; mid vmcnt(4)+barrier retires ks1 pair;
// stage next ks1 pair. Last tile: no stages, mid vmcnt(0). Never 0 in steady.
template <int ADD_RES, int WM, int WN, int MT, int NTT>
__global__ __launch_bounds__(WM * WN * 64, 2) void gemm_t(const bf16_t* __restrict__ A,
                                                          const bf16_t* __restrict__ Bw,
                                                          void* __restrict__ Cv,
                                                          const float* __restrict__ res,
                                                          int M, int N, int K) {
  constexpr int WAVES = WM * WN;
  constexpr int BM = WM * MT * 16;
  constexpr int BN = WN * NTT * 16;
  static_assert(BM == BN, "square tiles only");
  constexpr int RSZ  = BM * 64;      // bytes per ks region
  constexpr int BUFB = 4 * RSZ;      // bytes per dbuf (A ks0/ks1 + B ks0/ks1)
  constexpr int HALFROWS = WAVES * 16;
  __shared__ __align__(16) char LDS[2 * BUFB];
  const int tid = threadIdx.x;
  const int wave = tid >> 6, lane = tid & 63;
  const int wm = wave / WN, wn = wave % WN;

  // T1: XCD-aware bijective block swizzle (grids have nwg % 8 == 0)
  const int nbx = gridDim.x;
  const int nwg = nbx * gridDim.y;
  const int bid0 = blockIdx.y * nbx + blockIdx.x;
  const int cpx = nwg >> 3;
  const int bid = (bid0 & 7) * cpx + (bid0 >> 3);
  const int bm = bid / nbx, bn = bid % nbx;

  // staging addressing
  const int scg = (lane & 3) ^ ((lane >> 3) & 3);
  const bf16_t* Ag = A  + (size_t)(bm * BM + wave * 16 + (lane >> 2)) * K + scg * 8;
  const bf16_t* Bg = Bw + (size_t)(bn * BN + wave * 16 + (lane >> 2)) * K + scg * 8;
  const size_t rowHK = (size_t)HALFROWS * K;
  char* const LDSw = LDS + wave * 1024;

#define STG(u, mat, ks) do {                                              \
    char* d_ = LDSw + ((u) & 1) * BUFB + (mat) * 2 * RSZ + (ks) * RSZ;    \
    const bf16_t* s_ = (mat) ? Bg : Ag;                                   \
    const int ko_ = (u) * 64 + (ks) * 32;                                 \
    async_ld16(d_,           s_ + ko_);                                   \
    async_ld16(d_ + RSZ / 2, s_ + rowHK + ko_);                           \
  } while (0)

  const int NT = K >> 6;   // BK=64 tiles

  // prologue: stage tile0's 4 regions in retire order (A0, B0, A1, B1)
  STG(0, 0, 0); STG(0, 1, 0); STG(0, 0, 1); STG(0, 1, 1);

  f32x4 acc[MT][NTT];
  #pragma unroll
  for (int i = 0; i < MT; ++i)
    #pragma unroll
    for (int j = 0; j < NTT; ++j) acc[i][j] = (f32x4){0.f, 0.f, 0.f, 0.f};

  // fragment LDS byte offsets within a K-half region
  const int fr = lane & 15, fq = lane >> 4;
  int aoff[MT], boff[NTT];
  #pragma unroll
  for (int mt = 0; mt < MT; ++mt) {
    const int row = wm * MT * 16 + mt * 16 + fr;
    aoff[mt] = row * 64 + ((fq ^ ((row >> 1) & 3)) << 4);
  }
  #pragma unroll
  for (int nt = 0; nt < NTT; ++nt) {
    const int row = wn * NTT * 16 + nt * 16 + fr;
    boff[nt] = row * 64 + ((fq ^ ((row >> 1) & 3)) << 4);
  }

#define RDA(DST, bufb, ks, g) do {                                        \
    _Pragma("unroll")                                                     \
    for (int i_ = 0; i_ < 4; ++i_)                                        \
      DST[i_] = *(const bf16x8*)(LDS + (bufb) * BUFB + (ks) * RSZ + aoff[(g) * 4 + i_]); \
  } while (0)

#define RDB(DST, bufb, ks) do {                                           \
    _Pragma("unroll")                                                     \
    for (int i_ = 0; i_ < NTT; ++i_)                                      \
      DST[i_] = *(const bf16x8*)(LDS + (bufb) * BUFB + 2 * RSZ + (ks) * RSZ + boff[i_]); \
  } while (0)

#define MMx(AF, BF, g) do {                                               \
    _Pragma("unroll")                                                     \
    for (int m_ = 0; m_ < 4; ++m_)                                        \
      _Pragma("unroll")                                                   \
      for (int n_ = 0; n_ < NTT; ++n_)                                    \
        acc[(g) * 4 + m_][n_] = __builtin_amdgcn_mfma_f32_16x16x32_bf16(  \
            AF[m_], BF[n_], acc[(g) * 4 + m_][n_], 0, 0, 0);              \
  } while (0)

#define LGKM0 do { asm volatile("s_waitcnt lgkmcnt(0)" ::: "memory");     \
    __builtin_amdgcn_sched_barrier(0); } while (0)
#define VMB4 do { asm volatile("s_waitcnt vmcnt(4)" ::: "memory");        \
    __builtin_amdgcn_s_barrier(); } while (0)
#define VMB0 do { asm volatile("s_waitcnt vmcnt(0)" ::: "memory");        \
    __builtin_amdgcn_s_barrier(); } while (0)

#define KS_PHASE(t_, cb_, ks_, FULL) do {                                 \
    RDB(bq, cb_, ks_); RDA(aq, cb_, ks_, 0);                              \
    if (FULL) STG((t_) + 1, 0, ks_);                                      \
    if constexpr (MT == 8) {                                              \
      LGKM0; MMx(aq, bq, 0);                                              \
      RDA(aq2, cb_, ks_, 1);                                              \
      if (FULL) STG((t_) + 1, 1, ks_);                                    \
      LGKM0; MMx(aq2, bq, 1);                                             \
    } else {                                                              \
      if (FULL) STG((t_) + 1, 1, ks_);                                    \
      LGKM0; MMx(aq, bq, 0);                                              \
    }                                                                     \
  } while (0)

  bf16x8 aq[4], aq2[4], bq[NTT];
  (void)aq2;

  for (int t = 0; t < NT - 1; ++t) {
    const int cb = t & 1;
    VMB4; KS_PHASE(t, cb, 0, 1);   // ks0 of tile t valid
    VMB4; KS_PHASE(t, cb, 1, 1);   // ks1 of tile t valid
  }
  {
    const int cb = (NT - 1) & 1;
    VMB4; KS_PHASE(NT - 1, cb, 0, 0);
    VMB0; KS_PHASE(NT - 1, cb, 1, 0);
  }

#undef STG
#undef RDA
#undef RDB
#undef MMx
#undef LGKM0
#undef VMB4
#undef VMB0
#undef KS_PHASE

  // epilogue: D[row=fq*4+r][col=fr] per 16x16 tile
  const int m0 = bm * BM + wm * MT * 16 + fq * 4;
  const int n0 = bn * BN + wn * NTT * 16 + fr;
  #pragma unroll
  for (int mt = 0; mt < MT; ++mt)
    #pragma unroll
    for (int nt = 0; nt < NTT; ++nt)
      #pragma unroll
      for (int r = 0; r < 4; ++r) {
        const size_t m = (size_t)(m0 + mt * 16 + r);
        const size_t n = (size_t)(n0 + nt * 16);
        if (ADD_RES)
          ((float*)Cv)[m * N + n] = acc[mt][nt][r] + res[m * N + n];
        else
          ((bf16_t*)Cv)[m * N + n] = (bf16_t)acc[mt][nt][r];
      }
}

// ---------------- scan pass A: conv + chunk-local scan, carries only ----------------
// 8 channels/thread (16B loads), one block covers all 2048 channels of a chunk.
__global__ __launch_bounds__(256) void scanA_kernel(const bf16_t* __restrict__ xz,
                                                    const float* __restrict__ conv_w,
                                                    const float* __restrict__ conv_b,
                                                    const float* __restrict__ log_alpha,
                                                    float* __restrict__ carry) {
  const int chunk = blockIdx.x & (NCH - 1);
  const int b     = blockIdx.x >> 7;
  const int ch    = threadIdx.x * 8;
  const float alpha = sigmoidf_(log_alpha[ch >> 8]);
  float w[8][4], bias[8];
  #pragma unroll
  for (int j = 0; j < 8; ++j) {
    const float4 cw = ((const float4*)conv_w)[ch + j];
    w[j][0] = cw.x; w[j][1] = cw.y; w[j][2] = cw.z; w[j][3] = cw.w;
    bias[j] = conv_b[ch + j];
  }
  const int s0 = chunk * CHUNK;
  const size_t base = ((size_t)b * Ss + s0) * XZN + ch;
  float x3[8], x2[8], x1[8], y[8];
  #pragma unroll
  for (int j = 0; j < 8; ++j) { x3[j] = x2[j] = x1[j] = y[j] = 0.f; }
  if (chunk > 0) {
    const bf16x8 v3 = *(const bf16x8*)(xz + base - 3 * (size_t)XZN);
    const bf16x8 v2 = *(const bf16x8*)(xz + base - 2 * (size_t)XZN);
    const bf16x8 v1 = *(const bf16x8*)(xz + base - 1 * (size_t)XZN);
    #pragma unroll
    for (int j = 0; j < 8; ++j) { x3[j] = (float)v3[j]; x2[j] = (float)v2[j]; x1[j] = (float)v1[j]; }
  }
  #pragma unroll 2
  for (int t = 0; t < CHUNK; ++t) {
    const bf16x8 v = *(const bf16x8*)(xz + base + (size_t)t * XZN);
    #pragma unroll
    for (int j = 0; j < 8; ++j) {
      const float xc = (float)v[j];
      const float cv = bias[j] + w[j][0] * x3[j] + w[j][1] * x2[j] + w[j][2] * x1[j] + w[j][3] * xc;
      x3[j] = x2[j]; x2[j] = x1[j]; x1[j] = xc;
      y[j] = fmaf(alpha, y[j], cv);
    }
  }
  float* cp = carry + ((size_t)b * NCH + chunk) * DI + ch;
  *(float4*)cp       = make_float4(y[0], y[1], y[2], y[3]);
  *(float4*)(cp + 4) = make_float4(y[4], y[5], y[6], y[7]);
}

// ---------------- scan pass B: parallel weighted scan of chunk carries ----------------
__global__ __launch_bounds__(256) void scanB_kernel(const float* __restrict__ carry,
                                                    float* __restrict__ carryin,
                                                    const float* __restrict__ log_alpha) {
  __shared__ float S[8][32];
  const int b   = blockIdx.x >> 6;
  const int chg = blockIdx.x & 63;
  const int cg  = threadIdx.x >> 5;   // chunk-group 0..7
  const int chl = threadIdx.x & 31;
  const int ch  = chg * 32 + chl;
  const float alpha = sigmoidf_(log_alpha[ch >> 8]);
  const float lal  = log2f(alpha);
  const float aL   = exp2f((float)CHUNK * lal);        // alpha^32
  const float aL16 = exp2f((float)(CHUNK * 16) * lal); // alpha^512
  const size_t base = ((size_t)b * NCH + cg * 16) * DI + ch;
  float v[16];
  #pragma unroll
  for (int i = 0; i < 16; ++i) v[i] = carry[base + (size_t)i * DI];
  float Sl = v[0];
  #pragma unroll
  for (int i = 1; i < 16; ++i) Sl = fmaf(aL, Sl, v[i]);
  S[cg][chl] = Sl;
  __syncthreads();
  float P = 0.f;
  for (int h = 0; h < cg; ++h) P = fmaf(aL16, P, S[h][chl]);
  #pragma unroll
  for (int i = 0; i < 16; ++i) {
    carryin[base + (size_t)i * DI] = P;
    P = fmaf(aL, P, v[i]);
  }
}

// ---------------- scan pass C: recompute local scan seeded with carry-in, fuse SiLU*gate ----
// 8 channels/thread (16B loads for x, gate, and act write).
__global__ __launch_bounds__(256) void scanC_kernel(const bf16_t* __restrict__ xz,
                                                    const float* __restrict__ conv_w,
                                                    const float* __restrict__ conv_b,
                                                    const float* __restrict__ log_alpha,
                                                    const float* __restrict__ carryin,
                                                    bf16_t* __restrict__ act) {
  const int chunk = blockIdx.x & (NCH - 1);
  const int b     = blockIdx.x >> 7;
  const int ch    = threadIdx.x * 8;
  const float alpha = sigmoidf_(log_alpha[ch >> 8]);
  float w[8][4], bias[8];
  #pragma unroll
  for (int j = 0; j < 8; ++j) {
    const float4 cw = ((const float4*)conv_w)[ch + j];
    w[j][0] = cw.x; w[j][1] = cw.y; w[j][2] = cw.z; w[j][3] = cw.w;
    bias[j] = conv_b[ch + j];
  }
  const int s0 = chunk * CHUNK;
  const size_t base = ((size_t)b * Ss + s0) * XZN + ch;
  float x3[8], x2[8], x1[8], y[8];
  const float* cp = carryin + ((size_t)b * NCH + chunk) * DI + ch;
  const float4 ci0 = *(const float4*)cp;
  const float4 ci1 = *(const float4*)(cp + 4);
  y[0] = ci0.x; y[1] = ci0.y; y[2] = ci0.z; y[3] = ci0.w;
  y[4] = ci1.x; y[5] = ci1.y; y[6] = ci1.z; y[7] = ci1.w;
  #pragma unroll
  for (int j = 0; j < 8; ++j) { x3[j] = x2[j] = x1[j] = 0.f; }
  if (chunk > 0) {
    const bf16x8 v3 = *(const bf16x8*)(xz + base - 3 * (size_t)XZN);
    const bf16x8 v2 = *(const bf16x8*)(xz + base - 2 * (size_t)XZN);
    const bf16x8 v1 = *(const bf16x8*)(xz + base - 1 * (size_t)XZN);
    #pragma unroll
    for (int j = 0; j < 8; ++j) { x3[j] = (float)v3[j]; x2[j] = (float)v2[j]; x1[j] = (float)v1[j]; }
  }
  const size_t abase = ((size_t)b * Ss + s0) * DI + ch;
  #pragma unroll 2
  for (int t = 0; t < CHUNK; ++t) {
    const bf16x8 v  = *(const bf16x8*)(xz + base + (size_t)t * XZN);
    const bf16x8 gv = *(const bf16x8*)(xz + base + (size_t)t * XZN + DI);
    bf16x8 ov;
    #pragma unroll
    for (int j = 0; j < 8; ++j) {
      const float xc = (float)v[j];
      const float cv = bias[j] + w[j][0] * x3[j] + w[j][1] * x2[j] + w[j][2] * x1[j] + w[j][3] * xc;
      x3[j] = x2[j]; x2[j] = x1[j]; x1[j] = xc;
      y[j] = fmaf(alpha, y[j], cv);
      const float o = y[j] * (1.f / (1.f + __expf(-y[j]))) * (float)gv[j];
      ov[j] = (bf16_t)o;
    }
    *(bf16x8*)(act + abase + (size_t)t * DI) = ov;
  }
}

// ---------------- launch ----------------
extern "C" void kernel_launch(void* const* d_in, const int* in_sizes, int n_in,
                              void* d_out, int out_size, void* d_ws, size_t ws_size,
                              hipStream_t stream) {
  const float* x          = (const float*)d_in[0];
  const float* norm_w     = (const float*)d_in[1];
  const float* norm_b     = (const float*)d_in[2];
  const float* in_proj_w  = (const float*)d_in[3];
  const float* conv_w     = (const float*)d_in[4];
  const float* conv_b     = (const float*)d_in[5];
  const float* out_proj_w = (const float*)d_in[6];
  const float* log_alpha  = (const float*)d_in[7];
  float* out = (float*)d_out;

  char* ws = (char*)d_ws;
  bf16_t* xn     = (bf16_t*)(ws);                        // 32 MB (dead after GEMM1)
  bf16_t* w_in   = (bf16_t*)(ws + 33554432);             // 8 MB
  bf16_t* w_out  = (bf16_t*)(ws + 41943040);             // 4 MB
  bf16_t* xz     = (bf16_t*)(ws + 46137344);             // 128 MB
  bf16_t* act    = (bf16_t*)(ws + 180355072);            // 64 MB
  // carry buffers overlay the dead xn region (GEMM1 finished before scanA)
  float*  carry   = (float*)(ws);                        // 4 MB
  float*  carryin = (float*)(ws + 4194304);              // 4 MB

  cvt2_kernel<<<6144, 256, 0, stream>>>(in_proj_w, w_in, out_proj_w, w_out);
  ln_kernel<<<Mtot, 256, 0, stream>>>(x, norm_w, norm_b, xn);

  // GEMM1: 256x256 tiles, 8 waves (r4 best-measured config). 1024 blocks.
  dim3 g1(XZN / 256, Mtot / 256);
  gemm_t<0, 2, 4, 8, 4><<<g1, 512, 0, stream>>>(xn, w_in, xz, nullptr, Mtot, XZN, Dd);

  scanA_kernel<<<Bb * NCH, 256, 0, stream>>>(xz, conv_w, conv_b, log_alpha, carry);
  scanB_kernel<<<Bb * 64, 256, 0, stream>>>(carry, carryin, log_alpha);
  scanC_kernel<<<Bb * NCH, 256, 0, stream>>>(xz, conv_w, conv_b, log_alpha, carryin, act);

  // GEMM2: 128x128 tiles, 4 waves, 64KB LDS -> 1024 blocks = 2 blocks/CU x 2
  // rounds (block-level TLP hides prologue fill + res/write epilogue burst).
  dim3 g2(Dd / 128, Mtot / 128);
  gemm_t<1, 2, 2, 4, 4><<<g2, 256, 0, stream>>>(act, w_out, out, x, Mtot, Dd, DI);
}